// Round 6
// baseline (20013.791 us; speedup 1.0000x reference)
//
#include <hip/hip_runtime.h>

#define SEQ    8192
#define HID    100
#define G4     400      // 4*HID gate rows
#define NCLS   20
#define CH     32       // steps per staged x_proj chunk
#define NCH    (SEQ / CH)
#define PSTEPS 32768    // probe step count (4x SEQ, keeps it distinguishable)

typedef float v2f __attribute__((ext_vector_type(2)));
typedef float v4f __attribute__((ext_vector_type(4)));

__device__ __forceinline__ float fast_sigmoid(float x) {
    return 1.0f / (1.0f + __expf(-x));
}
__device__ __forceinline__ float fast_tanh(float x) {
    float e = __expf(2.0f * x);          // saturates correctly at +/-inf
    return 1.0f - 2.0f / (e + 1.0f);
}

// Raw barrier: drains LDS ops only (lgkmcnt), NOT vmcnt.
__device__ __forceinline__ void wg_barrier() {
    asm volatile("s_waitcnt lgkmcnt(0)" ::: "memory");
    __builtin_amdgcn_s_barrier();
    asm volatile("" ::: "memory");
}

// Cross-lane add via DPP quad_perm (VALU pipe, not LDS).
template<int CTRL>
__device__ __forceinline__ float dpp_add(float x) {
    int p = __builtin_amdgcn_update_dpp(0, __float_as_int(x), CTRL, 0xF, 0xF, true);
    return x + __int_as_float(p);
}
__device__ __forceinline__ float quad_allreduce(float x) {
    return dpp_add<0x4E>(dpp_add<0xB1>(x));
}

// ---------------------------------------------------------------------------
// Kernel 1: x_proj[t][j] = dot(emb[seq[t]], W_ih[j]) + b_ih[j] + b_hh[j]
// Output PERMUTED: gate row j=c*100+r -> slot r*4+c.
// ---------------------------------------------------------------------------
__global__ __launch_bounds__(512)
void xproj_kernel(const int* __restrict__ seq, const float* __restrict__ emb,
                  const float* __restrict__ Wih, const float* __restrict__ bih,
                  const float* __restrict__ bhh, float* __restrict__ xp)
{
    __shared__ float er[16][HID];
    const int tid = threadIdx.x;
    const int t0  = blockIdx.x * 16;

    if (tid < 400) {
        int r = tid / 25, q = tid - r * 25;
        int s = seq[t0 + r];
        *(float4*)&er[r][4 * q] = *(const float4*)&emb[(size_t)s * HID + 4 * q];
    }
    __syncthreads();

    const int row = (tid < G4) ? tid : (G4 - 1);
    const float4* wr = (const float4*)(Wih + (size_t)row * HID);
    const float bias = bih[row] + bhh[row];

    float acc[16];
    #pragma unroll
    for (int u = 0; u < 16; ++u) acc[u] = bias;

    #pragma unroll
    for (int k = 0; k < 25; ++k) {
        float4 wv = wr[k];
        #pragma unroll
        for (int u = 0; u < 16; ++u) {
            float4 ev = *(const float4*)&er[u][4 * k];
            acc[u] = fmaf(wv.x, ev.x, acc[u]);
            acc[u] = fmaf(wv.y, ev.y, acc[u]);
            acc[u] = fmaf(wv.z, ev.z, acc[u]);
            acc[u] = fmaf(wv.w, ev.w, acc[u]);
        }
    }
    if (tid < G4) {
        const int cj = row / HID, rj = row - cj * HID;
        const int pj = rj * 4 + cj;
        #pragma unroll
        for (int u = 0; u < 16; ++u)
            xp[(size_t)(t0 + u) * G4 + pj] = acc[u];
    }
}

// ---------------------------------------------------------------------------
// Kernel 2: persistent single-workgroup LSTM scan, 512 threads / 8 waves
// (R3 layout: thread = (r = tid>>2, k-slice s = tid&3), DPP quad reduce).
// R6 changes vs R3:
//  - x_proj staged in 32-step double-buffered LDS chunks => ZERO global
//    loads in the step loop (if R3's per-step prefetch compiled to
//    flat_load, it counted in lgkmcnt and every wg_barrier ate an L2/HBM
//    round trip; chunking amortizes that to ~28cy/step worst case)
//  - lo/hi FMA chains split: 14-deep -> 7-deep dependent chains
// ---------------------------------------------------------------------------
template<int MODE>
__global__ __launch_bounds__(512)
__attribute__((amdgpu_waves_per_eu(2, 2)))
void lstm_scan(const float* xp,
               const float* __restrict__ Whh,
               const float* __restrict__ fcw, const float* __restrict__ fcb,
               const int* __restrict__ seq, const float* __restrict__ emb,
               const float* __restrict__ Wih, const float* __restrict__ bih,
               const float* __restrict__ bhh,
               float* __restrict__ out)
{
    __shared__ v4f h4[2][32];             // double-buffered h
    __shared__ v4f xc[2][CH * HID];       // staged x_proj chunks (102400 B)

    const int tid = threadIdx.x;
    const int s   = tid & 3;
    const int rg  = tid >> 2;
    const int r   = (rg < HID) ? rg : (HID - 1);
    const bool live = (rg < HID);

    int qi[7];
    #pragma unroll
    for (int j = 0; j < 7; ++j) qi[j] = (j < 6) ? (s + 4 * j) : 24;

    v4f w[4][7];
    #pragma unroll
    for (int c = 0; c < 4; ++c) {
        const float* wr = Whh + (size_t)(c * HID + r) * HID;
        #pragma unroll
        for (int j = 0; j < 7; ++j) {
            v4f t = *(const v4f*)(wr + 4 * qi[j]);
            if (s != 0 && j == 6) t = (v4f){0.f, 0.f, 0.f, 0.f};
            w[c][j] = t;
        }
    }
    #pragma unroll
    for (int c = 0; c < 4; ++c)
        #pragma unroll
        for (int j = 0; j < 7; ++j)
            asm volatile("" : "+v"(w[c][j]));

    v4f bias4 = {0.f, 0.f, 0.f, 0.f};
    if constexpr (MODE == 1) {
        #pragma unroll
        for (int c = 0; c < 4; ++c)
            ((float*)&bias4)[c] = bih[c * HID + r] + bhh[c * HID + r];
    }

    if (tid < 128) ((float*)h4)[tid] = 0.0f;
    float cst = 0.0f;

    if constexpr (MODE == 0) {            // stage chunk 0
        const v4f* src0 = (const v4f*)xp;
        #pragma unroll
        for (int k = 0; k < 7; ++k) {
            int slot = tid + 512 * k;
            if (slot < CH * HID) xc[0][slot] = src0[slot];
        }
    }
    __syncthreads();

    if constexpr (MODE == 0) {
        #pragma unroll 1
        for (int cb = 0; cb < NCH; ++cb) {
            const int cur = cb & 1;
            const bool more = (cb + 1 < NCH);

            v4f g[7];                      // next-chunk loads, hidden under 32 steps
            if (more) {
                const v4f* src = (const v4f*)xp + (size_t)(cb + 1) * (CH * HID);
                #pragma unroll
                for (int k = 0; k < 6; ++k) g[k] = src[tid + 512 * k];
                if (tid < CH * HID - 512 * 6) g[6] = src[tid + 512 * 6];
            }

            const v4f* xrow = &xc[cur][r];
            #pragma unroll 1
            for (int u8 = 0; u8 < CH; u8 += 8) {
                #pragma unroll
                for (int v = 0; v < 8; ++v) {
                    const v4f* hb = h4[v & 1];
                    v4f xpv = xrow[(u8 + v) * HID];

                    v2f a0l = {0.f,0.f}, a0h = {0.f,0.f};
                    v2f a1l = {0.f,0.f}, a1h = {0.f,0.f};
                    v2f a2l = {0.f,0.f}, a2h = {0.f,0.f};
                    v2f a3l = {0.f,0.f}, a3h = {0.f,0.f};
                    #pragma unroll
                    for (int j = 0; j < 7; ++j) {
                        v4f hv = hb[qi[j]];
                        a0l = __builtin_elementwise_fma(w[0][j].lo, hv.lo, a0l);
                        a0h = __builtin_elementwise_fma(w[0][j].hi, hv.hi, a0h);
                        a1l = __builtin_elementwise_fma(w[1][j].lo, hv.lo, a1l);
                        a1h = __builtin_elementwise_fma(w[1][j].hi, hv.hi, a1h);
                        a2l = __builtin_elementwise_fma(w[2][j].lo, hv.lo, a2l);
                        a2h = __builtin_elementwise_fma(w[2][j].hi, hv.hi, a2h);
                        a3l = __builtin_elementwise_fma(w[3][j].lo, hv.lo, a3l);
                        a3h = __builtin_elementwise_fma(w[3][j].hi, hv.hi, a3h);
                    }
                    v2f t0 = a0l + a0h, t1 = a1l + a1h;
                    v2f t2 = a2l + a2h, t3 = a3l + a3h;
                    float gi = quad_allreduce(t0.x + t0.y) + xpv.x;
                    float gf = quad_allreduce(t1.x + t1.y) + xpv.y;
                    float gg = quad_allreduce(t2.x + t2.y) + xpv.z;
                    float go = quad_allreduce(t3.x + t3.y) + xpv.w;

                    gi = fast_sigmoid(gi);
                    gf = fast_sigmoid(gf);
                    gg = fast_tanh(gg);
                    go = fast_sigmoid(go);

                    cst = fmaf(gf, cst, gi * gg);
                    float hn = go * fast_tanh(cst);
                    if (live && s == 0)
                        ((float*)h4[(v & 1) ^ 1])[r] = hn;
                    wg_barrier();
                }
            }

            if (more) {
                #pragma unroll
                for (int k = 0; k < 6; ++k) xc[cur ^ 1][tid + 512 * k] = g[k];
                if (tid < CH * HID - 512 * 6) xc[cur ^ 1][tid + 512 * 6] = g[6];
                wg_barrier();
            }
        }
    } else {
        __shared__ v4f er4[25];
        #pragma unroll 1
        for (int t = 0; t < SEQ; ++t) {
            if (tid < 25) {
                int sq = seq[t];
                er4[tid] = *(const v4f*)(emb + (size_t)sq * HID + 4 * tid);
            }
            wg_barrier();

            const v4f* hb = h4[t & 1];
            v2f a0 = {0.f,0.f}, a1 = {0.f,0.f}, a2 = {0.f,0.f}, a3 = {0.f,0.f};
            #pragma unroll
            for (int j = 0; j < 7; ++j) {
                v4f hv = hb[qi[j]];
                v4f ev = er4[qi[j]];
                #pragma unroll
                for (int c = 0; c < 4; ++c) {
                    v4f wq = *(const v4f*)(Wih + (size_t)(c * HID + r) * HID + 4 * qi[j]);
                    if (s != 0 && j == 6) wq = (v4f){0.f, 0.f, 0.f, 0.f};
                    v2f* ac = (c == 0) ? &a0 : (c == 1) ? &a1 : (c == 2) ? &a2 : &a3;
                    *ac = __builtin_elementwise_fma(w[c][j].lo, hv.lo, *ac);
                    *ac = __builtin_elementwise_fma(w[c][j].hi, hv.hi, *ac);
                    *ac = __builtin_elementwise_fma(wq.lo, ev.lo, *ac);
                    *ac = __builtin_elementwise_fma(wq.hi, ev.hi, *ac);
                }
            }
            float gi = quad_allreduce(a0.x + a0.y) + ((float*)&bias4)[0];
            float gf = quad_allreduce(a1.x + a1.y) + ((float*)&bias4)[1];
            float gg = quad_allreduce(a2.x + a2.y) + ((float*)&bias4)[2];
            float go = quad_allreduce(a3.x + a3.y) + ((float*)&bias4)[3];

            gi = fast_sigmoid(gi);
            gf = fast_sigmoid(gf);
            gg = fast_tanh(gg);
            go = fast_sigmoid(go);

            cst = fmaf(gf, cst, gi * gg);
            float hn = go * fast_tanh(cst);
            if (live && s == 0)
                ((float*)h4[(t & 1) ^ 1])[r] = hn;
            wg_barrier();
        }
    }

    if (tid < NCLS) {
        const float* hf = (const float*)h4[0];
        const float* fr = fcw + (size_t)tid * HID;
        float acc = fcb[tid];
        #pragma unroll
        for (int k = 0; k < HID; ++k) acc = fmaf(fr[k], hf[k], acc);
        out[tid] = acc;
    }
}

// ---------------------------------------------------------------------------
// DIAGNOSTIC probe: structural skeleton of one scan step (barrier + 7
// broadcast ds_read_b128 + 28 pk-FMA in 7-deep chains + DPP quad reduce +
// fake 1-FMA "activations" + h write), PSTEPS times on junk data in d_ws.
// probe_dur/PSTEPS = the per-step floor of this sync/LDS topology; the
// difference to scan_step is the transcendental+chain surplus. Deterministic
// (reads xproj output / poisoned ws), writes only to d_ws.
// ---------------------------------------------------------------------------
__global__ __launch_bounds__(512)
__attribute__((amdgpu_waves_per_eu(2, 2)))
void probe_kernel(const float* wsrc, float* wdst)
{
    __shared__ v4f h4[2][32];
    __shared__ v4f xq[32];

    const int tid = threadIdx.x;
    const int s   = tid & 3;
    const int rg  = tid >> 2;
    const int r   = (rg < HID) ? rg : (HID - 1);
    const bool live = (rg < HID);

    int qi[7];
    #pragma unroll
    for (int j = 0; j < 7; ++j) qi[j] = (j < 6) ? (s + 4 * j) : 24;

    const v4f* src = (const v4f*)wsrc;
    v4f w[4][7];
    #pragma unroll
    for (int c = 0; c < 4; ++c)
        #pragma unroll
        for (int j = 0; j < 7; ++j)
            w[c][j] = src[(tid * 28 + c * 7 + j) & 2047];
    #pragma unroll
    for (int c = 0; c < 4; ++c)
        #pragma unroll
        for (int j = 0; j < 7; ++j)
            asm volatile("" : "+v"(w[c][j]));

    if (tid < 128) {
        ((float*)h4)[tid]       = 0.001f * tid;
        ((float*)h4)[tid + 128] = 0.0005f * tid;
    }
    if (tid < 32) xq[tid] = src[tid + 4096];
    __syncthreads();

    float cst = 0.0f;
    #pragma unroll 1
    for (int t8 = 0; t8 < PSTEPS; t8 += 8) {
        #pragma unroll
        for (int v = 0; v < 8; ++v) {
            const v4f* hb = h4[v & 1];
            v4f xpv = xq[r & 31];

            v2f a0l = {0.f,0.f}, a0h = {0.f,0.f};
            v2f a1l = {0.f,0.f}, a1h = {0.f,0.f};
            v2f a2l = {0.f,0.f}, a2h = {0.f,0.f};
            v2f a3l = {0.f,0.f}, a3h = {0.f,0.f};
            #pragma unroll
            for (int j = 0; j < 7; ++j) {
                v4f hv = hb[qi[j]];
                a0l = __builtin_elementwise_fma(w[0][j].lo, hv.lo, a0l);
                a0h = __builtin_elementwise_fma(w[0][j].hi, hv.hi, a0h);
                a1l = __builtin_elementwise_fma(w[1][j].lo, hv.lo, a1l);
                a1h = __builtin_elementwise_fma(w[1][j].hi, hv.hi, a1h);
                a2l = __builtin_elementwise_fma(w[2][j].lo, hv.lo, a2l);
                a2h = __builtin_elementwise_fma(w[2][j].hi, hv.hi, a2h);
                a3l = __builtin_elementwise_fma(w[3][j].lo, hv.lo, a3l);
                a3h = __builtin_elementwise_fma(w[3][j].hi, hv.hi, a3h);
            }
            v2f t0 = a0l + a0h, t1 = a1l + a1h;
            v2f t2 = a2l + a2h, t3 = a3l + a3h;
            float gi = quad_allreduce(t0.x + t0.y) + xpv.x;
            float gf = quad_allreduce(t1.x + t1.y) + xpv.y;
            float gg = quad_allreduce(t2.x + t2.y) + xpv.z;
            float go = quad_allreduce(t3.x + t3.y) + xpv.w;

            // fake activations: 1 FMA each (removes transcendental chain)
            gi = fmaf(gi, 0.125f, 0.03f);
            gf = fmaf(gf, 0.125f, 0.02f);
            gg = fmaf(gg, 0.125f, 0.01f);
            go = fmaf(go, 0.125f, 0.04f);

            cst = fmaf(gf, cst, gi * gg);
            float hn = go * (cst * 0.5f);
            if (live && s == 0)
                ((float*)h4[(v & 1) ^ 1])[r] = hn;
            wg_barrier();
        }
    }
    wdst[tid] = cst;       // keep everything live
}

// ---------------------------------------------------------------------------
extern "C" void kernel_launch(void* const* d_in, const int* in_sizes, int n_in,
                              void* d_out, int out_size, void* d_ws, size_t ws_size,
                              hipStream_t stream)
{
    const int*   seq = (const int*)d_in[0];
    const float* emb = (const float*)d_in[1];
    const float* Wih = (const float*)d_in[2];
    const float* Whh = (const float*)d_in[3];
    const float* bih = (const float*)d_in[4];
    const float* bhh = (const float*)d_in[5];
    const float* fcw = (const float*)d_in[6];
    const float* fcb = (const float*)d_in[7];
    float* out = (float*)d_out;
    float* xp  = (float*)d_ws;

    const size_t need = (size_t)SEQ * G4 * sizeof(float);
    if (ws_size >= need) {
        xproj_kernel<<<SEQ / 16, 512, 0, stream>>>(seq, emb, Wih, bih, bhh, xp);
        lstm_scan<0><<<1, 512, 0, stream>>>(xp, Whh, fcw, fcb,
                                            seq, emb, Wih, bih, bhh, out);
        // diagnostic probe AFTER the scan (clobbers ws only)
        probe_kernel<<<1, 512, 0, stream>>>((const float*)d_ws, (float*)d_ws);
    } else {
        lstm_scan<1><<<1, 512, 0, stream>>>(nullptr, Whh, fcw, fcb,
                                            seq, emb, Wih, bih, bhh, out);
    }
}

// Round 7
// 7697.823 us; speedup vs baseline: 2.5999x; 2.5999x over previous
//
#include <hip/hip_runtime.h>

#define SEQ  8192
#define HID  100
#define G4   400      // 4*HID gate rows
#define NCLS 20

typedef float v2f __attribute__((ext_vector_type(2)));
typedef float v4f __attribute__((ext_vector_type(4)));

__device__ __forceinline__ float fast_sigmoid(float x) {
    return 1.0f / (1.0f + __expf(-x));
}
__device__ __forceinline__ float fast_tanh(float x) {
    float e = __expf(2.0f * x);          // saturates correctly at +/-inf
    return 1.0f - 2.0f / (e + 1.0f);
}

// Raw barrier: drains LDS ops only (lgkmcnt), NOT vmcnt — register-ring
// global prefetch loads stay in flight across step barriers.
__device__ __forceinline__ void wg_barrier() {
    asm volatile("s_waitcnt lgkmcnt(0)" ::: "memory");
    __builtin_amdgcn_s_barrier();
    asm volatile("" ::: "memory");
}

// Cross-lane add via DPP quad_perm (VALU pipe, not the shared LDS pipe).
template<int CTRL>
__device__ __forceinline__ float dpp_add(float x) {
    int p = __builtin_amdgcn_update_dpp(0, __float_as_int(x), CTRL, 0xF, 0xF, true);
    return x + __int_as_float(p);
}
__device__ __forceinline__ float quad_allreduce(float x) {
    return dpp_add<0x4E>(dpp_add<0xB1>(x));
}

// ---------------------------------------------------------------------------
// Kernel 1: x_proj[t][j] = dot(emb[seq[t]], W_ih[j]) + b_ih[j] + b_hh[j]
// Output PERMUTED for the hrpt=2 scan: gate row j=c*100+r -> slot
// (r>>1)*8 + (r&1)*4 + c, so scan group g reads its 8 floats (4 gates x
// h-rows 2g,2g+1) as two contiguous v4f at xp[t*400 + 8g].
// ---------------------------------------------------------------------------
__global__ __launch_bounds__(512)
void xproj_kernel(const int* __restrict__ seq, const float* __restrict__ emb,
                  const float* __restrict__ Wih, const float* __restrict__ bih,
                  const float* __restrict__ bhh, float* __restrict__ xp)
{
    __shared__ float er[16][HID];
    const int tid = threadIdx.x;
    const int t0  = blockIdx.x * 16;

    if (tid < 400) {                       // 16 rows * 25 float4
        int r = tid / 25, q = tid - r * 25;
        int s = seq[t0 + r];
        *(float4*)&er[r][4 * q] = *(const float4*)&emb[(size_t)s * HID + 4 * q];
    }
    __syncthreads();

    const int row = (tid < G4) ? tid : (G4 - 1);
    const float4* wr = (const float4*)(Wih + (size_t)row * HID);
    const float bias = bih[row] + bhh[row];

    float acc[16];
    #pragma unroll
    for (int u = 0; u < 16; ++u) acc[u] = bias;

    #pragma unroll
    for (int k = 0; k < 25; ++k) {
        float4 wv = wr[k];
        #pragma unroll
        for (int u = 0; u < 16; ++u) {
            float4 ev = *(const float4*)&er[u][4 * k];
            acc[u] = fmaf(wv.x, ev.x, acc[u]);
            acc[u] = fmaf(wv.y, ev.y, acc[u]);
            acc[u] = fmaf(wv.z, ev.z, acc[u]);
            acc[u] = fmaf(wv.w, ev.w, acc[u]);
        }
    }
    if (tid < G4) {
        const int cj = row / HID, rj = row - cj * HID;
        const int pj = (rj >> 1) * 8 + (rj & 1) * 4 + cj;  // hrpt=2 slot
        #pragma unroll
        for (int u = 0; u < 16; ++u)
            xp[(size_t)(t0 + u) * G4 + pj] = acc[u];
    }
}

// ---------------------------------------------------------------------------
// Kernel 2: persistent single-workgroup LSTM scan, 256 threads / 4 waves.
// Thread (g = tid>>2, s = tid&3): ALL EIGHT gate rows (4 gates x h-rows
// {2g, 2g+1}) over K-slice s (quads s,s+4..s+20, +24 on s==0).
//
// WHY (R6 probe): skeleton floor = 437ns/step, dominated by 56 broadcast
// ds_read_b128/step through the shared LDS pipe. hrpt=2 at 4 waves halves
// that to 28 and halves the redundant activation work. xp lives in a
// register prefetch ring (global_load -> vmcnt, invisible to the lgkm-only
// barrier). Weights: 56 v4f/thread; launch_bounds(256,1) => 512-reg budget
// (AGPR parking is fine: gfx950 VALU reads AGPRs directly — R5 falsified
// the accvgpr-tax theory).
// ---------------------------------------------------------------------------
__global__ __launch_bounds__(256, 1)
void lstm_scan(const float* xp,
               const float* __restrict__ Whh,
               const float* __restrict__ fcw, const float* __restrict__ fcb,
               float* __restrict__ out)
{
    __shared__ v4f h4[2][32];             // double-buffered h (100 of 128 used)

    const int tid = threadIdx.x;
    const int s   = tid & 3;                        // K-slice (== DPP quad lane)
    const int g   = tid >> 2;                       // 0..63
    const int gc  = (g < 50) ? g : 49;              // clamp idle groups
    const bool live = (g < 50);

    int qi[7];
    #pragma unroll
    for (int j = 0; j < 7; ++j) qi[j] = (j < 6) ? (s + 4 * j) : 24;

    // weights: 8 gate rows x 7 v4f = 56 v4f
    v4f w[8][7];
    #pragma unroll
    for (int p = 0; p < 2; ++p)
        #pragma unroll
        for (int c = 0; c < 4; ++c) {
            const float* wr = Whh + (size_t)(c * HID + 2 * gc + p) * HID;
            #pragma unroll
            for (int j = 0; j < 7; ++j) {
                v4f t = *(const v4f*)(wr + 4 * qi[j]);
                if (s != 0 && j == 6) t = (v4f){0.f, 0.f, 0.f, 0.f};
                w[p * 4 + c][j] = t;
            }
        }
    #pragma unroll
    for (int k = 0; k < 8; ++k)
        #pragma unroll
        for (int j = 0; j < 7; ++j)
            asm volatile("" : "+v"(w[k][j]));       // defeat remat/reload

    if (tid < 128) ((float*)h4)[tid] = 0.0f;        // zero h buffer 0
    float c0 = 0.0f, c1 = 0.0f;

    // xp register prefetch ring: 8 steps x 2 v4f
    v4f xn[8][2];
    #pragma unroll
    for (int u = 0; u < 8; ++u) {
        xn[u][0] = *(const v4f*)(xp + (size_t)u * G4 + 8 * gc);
        xn[u][1] = *(const v4f*)(xp + (size_t)u * G4 + 8 * gc + 4);
    }
    wg_barrier();

    #pragma unroll 1
    for (int t8 = 0; t8 < SEQ; t8 += 8) {
        #pragma unroll
        for (int u = 0; u < 8; ++u) {
            const int t = t8 + u;
            v4f xa = xn[u][0], xb = xn[u][1];
            if (t + 8 < SEQ) {            // prefetch 8 ahead (vmcnt only)
                xn[u][0] = *(const v4f*)(xp + (size_t)(t + 8) * G4 + 8 * gc);
                xn[u][1] = *(const v4f*)(xp + (size_t)(t + 8) * G4 + 8 * gc + 4);
            }

            // 8 gate partial dots over this thread's K-slice.
            // Separate lo/hi accumulators: 7-deep chains.
            const v4f* hb = h4[u & 1];
            v2f aL[8], aH[8];
            #pragma unroll
            for (int k = 0; k < 8; ++k) { aL[k] = (v2f){0.f, 0.f}; aH[k] = (v2f){0.f, 0.f}; }
            #pragma unroll
            for (int j = 0; j < 7; ++j) {
                v4f hv = hb[qi[j]];                  // 4-addr multicast read
                #pragma unroll
                for (int k = 0; k < 8; ++k) {
                    aL[k] = __builtin_elementwise_fma(w[k][j].lo, hv.lo, aL[k]);
                    aH[k] = __builtin_elementwise_fma(w[k][j].hi, hv.hi, aH[k]);
                }
            }

            float G[8];
            #pragma unroll
            for (int k = 0; k < 8; ++k) {
                v2f t2 = aL[k] + aH[k];
                G[k] = quad_allreduce(t2.x + t2.y);
            }
            G[0] += xa.x; G[1] += xa.y; G[2] += xa.z; G[3] += xa.w;
            G[4] += xb.x; G[5] += xb.y; G[6] += xb.z; G[7] += xb.w;

            // h-row 2g
            float i0 = fast_sigmoid(G[0]);
            float f0 = fast_sigmoid(G[1]);
            float g0 = fast_tanh(G[2]);
            float o0 = fast_sigmoid(G[3]);
            c0 = fmaf(f0, c0, i0 * g0);
            float h0 = o0 * fast_tanh(c0);
            // h-row 2g+1
            float i1 = fast_sigmoid(G[4]);
            float f1 = fast_sigmoid(G[5]);
            float g1 = fast_tanh(G[6]);
            float o1 = fast_sigmoid(G[7]);
            c1 = fmaf(f1, c1, i1 * g1);
            float h1 = o1 * fast_tanh(c1);

            if (live && s == 0) {
                float2 hw = make_float2(h0, h1);
                *(float2*)&((float*)h4[(u & 1) ^ 1])[2 * gc] = hw;  // b64 write
            }
            wg_barrier();                             // ONE barrier/step
        }
    }

    // final FC: out[20] = fc_w @ h_last + fc_b  (SEQ even -> h_last in h4[0])
    if (tid < NCLS) {
        const float* hf = (const float*)h4[0];
        const float* fr = fcw + (size_t)tid * HID;
        float acc = fcb[tid];
        #pragma unroll
        for (int k = 0; k < HID; ++k) acc = fmaf(fr[k], hf[k], acc);
        out[tid] = acc;
    }
}

// ---------------------------------------------------------------------------
// Fallback for tiny workspace (never triggered so far): R6 MODE1 structure,
// 512 threads, inline input projection. Slow but correct.
// ---------------------------------------------------------------------------
__global__ __launch_bounds__(512)
__attribute__((amdgpu_waves_per_eu(2, 2)))
void lstm_scan_small(const int* __restrict__ seq, const float* __restrict__ emb,
                     const float* __restrict__ Wih, const float* __restrict__ Whh,
                     const float* __restrict__ bih, const float* __restrict__ bhh,
                     const float* __restrict__ fcw, const float* __restrict__ fcb,
                     float* __restrict__ out)
{
    __shared__ v4f h4[2][32];
    __shared__ v4f er4[25];

    const int tid = threadIdx.x;
    const int s   = tid & 3;
    const int rg  = tid >> 2;
    const int r   = (rg < HID) ? rg : (HID - 1);
    const bool live = (rg < HID);

    int qi[7];
    #pragma unroll
    for (int j = 0; j < 7; ++j) qi[j] = (j < 6) ? (s + 4 * j) : 24;

    v4f w[4][7];
    #pragma unroll
    for (int c = 0; c < 4; ++c) {
        const float* wr = Whh + (size_t)(c * HID + r) * HID;
        #pragma unroll
        for (int j = 0; j < 7; ++j) {
            v4f t = *(const v4f*)(wr + 4 * qi[j]);
            if (s != 0 && j == 6) t = (v4f){0.f, 0.f, 0.f, 0.f};
            w[c][j] = t;
        }
    }

    v4f bias4;
    #pragma unroll
    for (int c = 0; c < 4; ++c)
        ((float*)&bias4)[c] = bih[c * HID + r] + bhh[c * HID + r];

    if (tid < 128) ((float*)h4)[tid] = 0.0f;
    float cst = 0.0f;
    __syncthreads();

    #pragma unroll 1
    for (int t = 0; t < SEQ; ++t) {
        if (tid < 25) {
            int sq = seq[t];
            er4[tid] = *(const v4f*)(emb + (size_t)sq * HID + 4 * tid);
        }
        wg_barrier();

        const v4f* hb = h4[t & 1];
        v2f a0 = {0.f,0.f}, a1 = {0.f,0.f}, a2 = {0.f,0.f}, a3 = {0.f,0.f};
        #pragma unroll
        for (int j = 0; j < 7; ++j) {
            v4f hv = hb[qi[j]];
            v4f ev = er4[qi[j]];
            #pragma unroll
            for (int c = 0; c < 4; ++c) {
                v4f wq = *(const v4f*)(Wih + (size_t)(c * HID + r) * HID + 4 * qi[j]);
                if (s != 0 && j == 6) wq = (v4f){0.f, 0.f, 0.f, 0.f};
                v2f* ac = (c == 0) ? &a0 : (c == 1) ? &a1 : (c == 2) ? &a2 : &a3;
                *ac = __builtin_elementwise_fma(w[c][j].lo, hv.lo, *ac);
                *ac = __builtin_elementwise_fma(w[c][j].hi, hv.hi, *ac);
                *ac = __builtin_elementwise_fma(wq.lo, ev.lo, *ac);
                *ac = __builtin_elementwise_fma(wq.hi, ev.hi, *ac);
            }
        }
        float gi = quad_allreduce(a0.x + a0.y) + ((float*)&bias4)[0];
        float gf = quad_allreduce(a1.x + a1.y) + ((float*)&bias4)[1];
        float gg = quad_allreduce(a2.x + a2.y) + ((float*)&bias4)[2];
        float go = quad_allreduce(a3.x + a3.y) + ((float*)&bias4)[3];

        gi = fast_sigmoid(gi);
        gf = fast_sigmoid(gf);
        gg = fast_tanh(gg);
        go = fast_sigmoid(go);

        cst = fmaf(gf, cst, gi * gg);
        float hn = go * fast_tanh(cst);
        if (live && s == 0)
            ((float*)h4[(t & 1) ^ 1])[r] = hn;
        wg_barrier();
    }

    if (tid < NCLS) {
        const float* hf = (const float*)h4[0];
        const float* fr = fcw + (size_t)tid * HID;
        float acc = fcb[tid];
        #pragma unroll
        for (int k = 0; k < HID; ++k) acc = fmaf(fr[k], hf[k], acc);
        out[tid] = acc;
    }
}

// ---------------------------------------------------------------------------
extern "C" void kernel_launch(void* const* d_in, const int* in_sizes, int n_in,
                              void* d_out, int out_size, void* d_ws, size_t ws_size,
                              hipStream_t stream)
{
    const int*   seq = (const int*)d_in[0];
    const float* emb = (const float*)d_in[1];
    const float* Wih = (const float*)d_in[2];
    const float* Whh = (const float*)d_in[3];
    const float* bih = (const float*)d_in[4];
    const float* bhh = (const float*)d_in[5];
    const float* fcw = (const float*)d_in[6];
    const float* fcb = (const float*)d_in[7];
    float* out = (float*)d_out;
    float* xp  = (float*)d_ws;

    const size_t need = (size_t)SEQ * G4 * sizeof(float);
    if (ws_size >= need) {
        xproj_kernel<<<SEQ / 16, 512, 0, stream>>>(seq, emb, Wih, bih, bhh, xp);
        lstm_scan<<<1, 256, 0, stream>>>(xp, Whh, fcw, fcb, out);
    } else {
        lstm_scan_small<<<1, 512, 0, stream>>>(seq, emb, Wih, Whh,
                                               bih, bhh, fcw, fcb, out);
    }
}

// Round 8
// 6261.897 us; speedup vs baseline: 3.1961x; 1.2293x over previous
//
#include <hip/hip_runtime.h>

#define SEQ  8192
#define HID  100
#define G4   400      // 4*HID gate rows
#define NCLS 20

typedef float v2f __attribute__((ext_vector_type(2)));
typedef float v4f __attribute__((ext_vector_type(4)));

// Raw barrier: drains LDS ops only (lgkmcnt), NOT vmcnt — register-ring
// global prefetch loads stay in flight across step barriers.
__device__ __forceinline__ void wg_barrier() {
    asm volatile("s_waitcnt lgkmcnt(0)" ::: "memory");
    __builtin_amdgcn_s_barrier();
    asm volatile("" ::: "memory");
}

// DPP move (VALU pipe). CTRL: 0xB1=xor1(quad_perm 1,0,3,2),
// 0x4E=xor2(2,3,0,1), 0x141=row_half_mirror (s <-> 7-s within 8),
// 0x55/0xAA/0xFF = quad_perm broadcast of position 1/2/3.
template<int CTRL>
__device__ __forceinline__ float dpp_mov(float x) {
    return __int_as_float(
        __builtin_amdgcn_update_dpp(0, __float_as_int(x), CTRL, 0xF, 0xF, true));
}

// ---------------------------------------------------------------------------
// Kernel 1: x_proj[t][j] = dot(emb[seq[t]], W_ih[j]) + b_ih[j] + b_hh[j]
// Output PERMUTED: gate row j=c*100+r (p=r&1, grp=r>>1) -> slot
// grp*8 + c*2 + p, so scan lane (g, s) reads its float2 {row 2g, row 2g+1}
// for gate min(s,7-s) at xp[t*400 + 8g + 2*gate].
// ---------------------------------------------------------------------------
__global__ __launch_bounds__(512)
void xproj_kernel(const int* __restrict__ seq, const float* __restrict__ emb,
                  const float* __restrict__ Wih, const float* __restrict__ bih,
                  const float* __restrict__ bhh, float* __restrict__ xp)
{
    __shared__ float er[16][HID];
    const int tid = threadIdx.x;
    const int t0  = blockIdx.x * 16;

    if (tid < 400) {                       // 16 rows * 25 float4
        int r = tid / 25, q = tid - r * 25;
        int s = seq[t0 + r];
        *(float4*)&er[r][4 * q] = *(const float4*)&emb[(size_t)s * HID + 4 * q];
    }
    __syncthreads();

    const int row = (tid < G4) ? tid : (G4 - 1);
    const float4* wr = (const float4*)(Wih + (size_t)row * HID);
    const float bias = bih[row] + bhh[row];

    float acc[16];
    #pragma unroll
    for (int u = 0; u < 16; ++u) acc[u] = bias;

    #pragma unroll
    for (int k = 0; k < 25; ++k) {
        float4 wv = wr[k];
        #pragma unroll
        for (int u = 0; u < 16; ++u) {
            float4 ev = *(const float4*)&er[u][4 * k];
            acc[u] = fmaf(wv.x, ev.x, acc[u]);
            acc[u] = fmaf(wv.y, ev.y, acc[u]);
            acc[u] = fmaf(wv.z, ev.z, acc[u]);
            acc[u] = fmaf(wv.w, ev.w, acc[u]);
        }
    }
    if (tid < G4) {
        const int cj = row / HID, rj = row - cj * HID;
        const int pj = (rj >> 1) * 8 + cj * 2 + (rj & 1);  // new permute
        #pragma unroll
        for (int u = 0; u < 16; ++u)
            xp[(size_t)(t0 + u) * G4 + pj] = acc[u];
    }
}

// ---------------------------------------------------------------------------
// Kernel 2: persistent single-workgroup LSTM scan, 512 threads / 8 waves
// (2 waves/SIMD: R7 proved 1/SIMD serializes; R6 probe fixed the 8-wave
// skeleton floor at the LDS pipe). Thread (g = tid>>3, s = tid&7):
//  - FMA: partial dots for ALL 8 gate rows (4 gates x h-rows 2g,2g+1) over
//    K-quads {s, s+8, 16+s, 24(dummy 0 unless s==0)} -> 4 ds_read_b128 and
//    64 v2f FMA per thread; LDS reads/step: 64 -> 32 wave-instrs.
//  - DPP reduce-SCATTER (xor1 -> sel(b1) -> xor2 -> sel(b2) -> half_mirror):
//    lane s ends with gate min(s,7-s) fully reduced, all registers
//    statically indexed, all on the VALU pipe.
//  - act-scatter: each lane does ONE activation (unified 1 - m/(e^{kx}+1):
//    sigma m=k=1, tanh m=k=2) -> trans issue cut 4x vs redundant form.
//  - gather i,f,g,o to lane s==0 via 3 quad_perm broadcasts; c,h in lane 0;
//    one ds_write_b64 per group; ONE barrier/step.
//  - xp: per-lane float2 register ring, 4 deep (vmcnt only, invisible to
//    the lgkm-only barrier).
// ---------------------------------------------------------------------------
__global__ __launch_bounds__(512)
__attribute__((amdgpu_waves_per_eu(2, 2)))
void lstm_scan(const float* xp,
               const float* __restrict__ Whh,
               const float* __restrict__ fcw, const float* __restrict__ fcb,
               float* __restrict__ out)
{
    __shared__ v4f h4[2][32];             // double-buffered h (100 of 128 used)

    const int tid = threadIdx.x;
    const int s   = tid & 7;                        // K-slice / gate lane
    const int g   = tid >> 3;                       // 0..63
    const int gl  = (g < 50) ? g : 49;              // clamp idle groups
    const bool live = (g < 50);

    const int gate = (s < 4) ? s : (7 - s);         // min(s, 7-s)
    const bool b1 = (((s & 1) ^ (s >> 2)) != 0);    // stage-1 keep bit
    const bool b2 = ((((s >> 1) & 1) ^ (s >> 2)) != 0); // stage-2 keep bit
    const float kk = (gate == 2) ? 2.0f : 1.0f;     // act scale
    const float mm = (gate == 2) ? 2.0f : 1.0f;     // act magnitude

    // K-quads for this lane (q3 dummy for s!=0: reads quad 24, weight=0)
    const int q0 = s, q1 = s + 8, q2 = 16 + s, q3 = 24;

    // W_hh slices: [row p][gate c][quad j] = 32 v4f = 128 VGPRs
    v4f wv[2][4][4];
    #pragma unroll
    for (int p = 0; p < 2; ++p)
        #pragma unroll
        for (int c = 0; c < 4; ++c) {
            const float* wr = Whh + (size_t)(c * HID + 2 * gl + p) * HID;
            wv[p][c][0] = *(const v4f*)(wr + 4 * q0);
            wv[p][c][1] = *(const v4f*)(wr + 4 * q1);
            wv[p][c][2] = *(const v4f*)(wr + 4 * q2);
            v4f t = *(const v4f*)(wr + 4 * q3);
            if (s != 0) t = (v4f){0.f, 0.f, 0.f, 0.f};
            wv[p][c][3] = t;
        }
    #pragma unroll
    for (int p = 0; p < 2; ++p)
        #pragma unroll
        for (int c = 0; c < 4; ++c)
            #pragma unroll
            for (int j = 0; j < 4; ++j)
                asm volatile("" : "+v"(wv[p][c][j]));   // defeat in-loop reload

    if (tid < 128) ((float*)h4)[tid] = 0.0f;        // zero h buffer 0
    float c0 = 0.0f, c1 = 0.0f;

    // xp register ring, 4 deep; lane address = t*400 + 8*gl + 2*gate
    const float* xbase = xp + 8 * gl + 2 * gate;
    float2 xn[4];
    #pragma unroll
    for (int u = 0; u < 4; ++u)
        xn[u] = *(const float2*)(xbase + (size_t)u * G4);
    __syncthreads();

    #pragma unroll 1
    for (int t8 = 0; t8 < SEQ; t8 += 8) {
        #pragma unroll
        for (int v = 0; v < 8; ++v) {
            const int t = t8 + v;
            float2 xv = xn[v & 3];
            if (t + 4 < SEQ)                      // prefetch 4 ahead
                xn[v & 3] = *(const float2*)(xbase + (size_t)(t + 4) * G4);

            // ---- partial dots: 4 broadcast b128 reads, 64 v2f FMA ----
            const v4f* hb = h4[t & 1];
            v4f hq0 = hb[q0], hq1 = hb[q1], hq2 = hb[q2], hq3 = hb[q3];

            float G[2][4];
            #pragma unroll
            for (int p = 0; p < 2; ++p)
                #pragma unroll
                for (int c = 0; c < 4; ++c) {
                    v2f aL = {0.f, 0.f}, aH = {0.f, 0.f};
                    aL = __builtin_elementwise_fma(wv[p][c][0].lo, hq0.lo, aL);
                    aH = __builtin_elementwise_fma(wv[p][c][0].hi, hq0.hi, aH);
                    aL = __builtin_elementwise_fma(wv[p][c][1].lo, hq1.lo, aL);
                    aH = __builtin_elementwise_fma(wv[p][c][1].hi, hq1.hi, aH);
                    aL = __builtin_elementwise_fma(wv[p][c][2].lo, hq2.lo, aL);
                    aH = __builtin_elementwise_fma(wv[p][c][2].hi, hq2.hi, aH);
                    aL = __builtin_elementwise_fma(wv[p][c][3].lo, hq3.lo, aL);
                    aH = __builtin_elementwise_fma(wv[p][c][3].hi, hq3.hi, aH);
                    v2f t2 = aL + aH;
                    G[p][c] = t2.x + t2.y;
                }

            // ---- DPP reduce-scatter: lane s ends with its gate's total ----
            // stage 1: add xor1 partner (all 8 accumulators)
            float G1[2][4];
            #pragma unroll
            for (int p = 0; p < 2; ++p)
                #pragma unroll
                for (int c = 0; c < 4; ++c)
                    G1[p][c] = G[p][c] + dpp_mov<0xB1>(G[p][c]);
            // select my gate pair (bit0 == b1): canonical regs
            float P0[2], P1[2];
            #pragma unroll
            for (int p = 0; p < 2; ++p) {
                P0[p] = b1 ? G1[p][1] : G1[p][0];
                P1[p] = b1 ? G1[p][3] : G1[p][2];
            }
            // stage 2: add xor2 partner (same pair set on partner)
            #pragma unroll
            for (int p = 0; p < 2; ++p) {
                P0[p] += dpp_mov<0x4E>(P0[p]);
                P1[p] += dpp_mov<0x4E>(P1[p]);
            }
            // select my gate (bit1 == b2)
            float Q[2];
            #pragma unroll
            for (int p = 0; p < 2; ++p) Q[p] = b2 ? P1[p] : P0[p];
            // stage 3: half_mirror (s <-> 7-s), valid in ALL lanes
            #pragma unroll
            for (int p = 0; p < 2; ++p) Q[p] += dpp_mov<0x141>(Q[p]);

            // ---- activation (one per lane): act = 1 - m/(e^{kx}+1) ----
            Q[0] += xv.x;
            Q[1] += xv.y;
            float A0 = 1.0f - mm * __frcp_rn(__expf(kk * Q[0]) + 1.0f);
            float A1 = 1.0f - mm * __frcp_rn(__expf(kk * Q[1]) + 1.0f);

            // ---- gather i,f,g,o to quad position 0 (lane s==0 valid) ----
            float f0 = dpp_mov<0x55>(A0), g0 = dpp_mov<0xAA>(A0), o0 = dpp_mov<0xFF>(A0);
            float f1 = dpp_mov<0x55>(A1), g1 = dpp_mov<0xAA>(A1), o1 = dpp_mov<0xFF>(A1);

            // c,h in lane s==0 (garbage elsewhere, never read)
            c0 = fmaf(f0, c0, A0 * g0);
            c1 = fmaf(f1, c1, A1 * g1);
            float th0 = 1.0f - 2.0f * __frcp_rn(__expf(2.0f * c0) + 1.0f);
            float th1 = 1.0f - 2.0f * __frcp_rn(__expf(2.0f * c1) + 1.0f);
            float h0 = o0 * th0;
            float h1 = o1 * th1;

            if (live && s == 0) {
                float2 hw = make_float2(h0, h1);
                *(float2*)&((float*)h4[(t & 1) ^ 1])[2 * gl] = hw;
            }
            wg_barrier();                          // ONE barrier/step
        }
    }

    // final FC: out[20] = fc_w @ h_last + fc_b  (SEQ even -> h_last in h4[0])
    if (tid < NCLS) {
        const float* hf = (const float*)h4[0];
        const float* fr = fcw + (size_t)tid * HID;
        float acc = fcb[tid];
        #pragma unroll
        for (int k = 0; k < HID; ++k) acc = fmaf(fr[k], hf[k], acc);
        out[tid] = acc;
    }
}

// ---------------------------------------------------------------------------
// Fallback for tiny workspace (never triggered so far): R6 MODE1 structure.
// ---------------------------------------------------------------------------
__global__ __launch_bounds__(512)
__attribute__((amdgpu_waves_per_eu(2, 2)))
void lstm_scan_small(const int* __restrict__ seq, const float* __restrict__ emb,
                     const float* __restrict__ Wih, const float* __restrict__ Whh,
                     const float* __restrict__ bih, const float* __restrict__ bhh,
                     const float* __restrict__ fcw, const float* __restrict__ fcb,
                     float* __restrict__ out)
{
    __shared__ v4f h4[2][32];
    __shared__ v4f er4[25];

    const int tid = threadIdx.x;
    const int s   = tid & 3;
    const int rg  = tid >> 2;
    const int r   = (rg < HID) ? rg : (HID - 1);
    const bool live = (rg < HID);

    int qi[7];
    #pragma unroll
    for (int j = 0; j < 7; ++j) qi[j] = (j < 6) ? (s + 4 * j) : 24;

    v4f w[4][7];
    #pragma unroll
    for (int c = 0; c < 4; ++c) {
        const float* wr = Whh + (size_t)(c * HID + r) * HID;
        #pragma unroll
        for (int j = 0; j < 7; ++j) {
            v4f t = *(const v4f*)(wr + 4 * qi[j]);
            if (s != 0 && j == 6) t = (v4f){0.f, 0.f, 0.f, 0.f};
            w[c][j] = t;
        }
    }

    v4f bias4;
    #pragma unroll
    for (int c = 0; c < 4; ++c)
        ((float*)&bias4)[c] = bih[c * HID + r] + bhh[c * HID + r];

    if (tid < 128) ((float*)h4)[tid] = 0.0f;
    float cst = 0.0f;
    __syncthreads();

    #pragma unroll 1
    for (int t = 0; t < SEQ; ++t) {
        if (tid < 25) {
            int sq = seq[t];
            er4[tid] = *(const v4f*)(emb + (size_t)sq * HID + 4 * tid);
        }
        wg_barrier();

        const v4f* hb = h4[t & 1];
        v2f a0 = {0.f,0.f}, a1 = {0.f,0.f}, a2 = {0.f,0.f}, a3 = {0.f,0.f};
        #pragma unroll
        for (int j = 0; j < 7; ++j) {
            v4f hv = hb[qi[j]];
            v4f ev = er4[qi[j]];
            #pragma unroll
            for (int c = 0; c < 4; ++c) {
                v4f wq = *(const v4f*)(Wih + (size_t)(c * HID + r) * HID + 4 * qi[j]);
                if (s != 0 && j == 6) wq = (v4f){0.f, 0.f, 0.f, 0.f};
                v2f* ac = (c == 0) ? &a0 : (c == 1) ? &a1 : (c == 2) ? &a2 : &a3;
                *ac = __builtin_elementwise_fma(w[c][j].lo, hv.lo, *ac);
                *ac = __builtin_elementwise_fma(w[c][j].hi, hv.hi, *ac);
                *ac = __builtin_elementwise_fma(wq.lo, ev.lo, *ac);
                *ac = __builtin_elementwise_fma(wq.hi, ev.hi, *ac);
            }
        }
        // quad allreduce via DPP
        float gi = a0.x + a0.y, gf = a1.x + a1.y, gg = a2.x + a2.y, go = a3.x + a3.y;
        gi += dpp_mov<0xB1>(gi); gi += dpp_mov<0x4E>(gi);
        gf += dpp_mov<0xB1>(gf); gf += dpp_mov<0x4E>(gf);
        gg += dpp_mov<0xB1>(gg); gg += dpp_mov<0x4E>(gg);
        go += dpp_mov<0xB1>(go); go += dpp_mov<0x4E>(go);
        gi += ((float*)&bias4)[0];
        gf += ((float*)&bias4)[1];
        gg += ((float*)&bias4)[2];
        go += ((float*)&bias4)[3];

        gi = 1.0f - __frcp_rn(__expf(gi) + 1.0f);
        gf = 1.0f - __frcp_rn(__expf(gf) + 1.0f);
        gg = 1.0f - 2.0f * __frcp_rn(__expf(2.0f * gg) + 1.0f);
        go = 1.0f - __frcp_rn(__expf(go) + 1.0f);

        cst = fmaf(gf, cst, gi * gg);
        float hn = go * (1.0f - 2.0f * __frcp_rn(__expf(2.0f * cst) + 1.0f));
        if (live && s == 0)
            ((float*)h4[(t & 1) ^ 1])[r] = hn;
        wg_barrier();
    }

    if (tid < NCLS) {
        const float* hf = (const float*)h4[0];
        const float* fr = fcw + (size_t)tid * HID;
        float acc = fcb[tid];
        #pragma unroll
        for (int k = 0; k < HID; ++k) acc = fmaf(fr[k], hf[k], acc);
        out[tid] = acc;
    }
}

// ---------------------------------------------------------------------------
extern "C" void kernel_launch(void* const* d_in, const int* in_sizes, int n_in,
                              void* d_out, int out_size, void* d_ws, size_t ws_size,
                              hipStream_t stream)
{
    const int*   seq = (const int*)d_in[0];
    const float* emb = (const float*)d_in[1];
    const float* Wih = (const float*)d_in[2];
    const float* Whh = (const float*)d_in[3];
    const float* bih = (const float*)d_in[4];
    const float* bhh = (const float*)d_in[5];
    const float* fcw = (const float*)d_in[6];
    const float* fcb = (const float*)d_in[7];
    float* out = (float*)d_out;
    float* xp  = (float*)d_ws;

    const size_t need = (size_t)SEQ * G4 * sizeof(float);
    if (ws_size >= need) {
        xproj_kernel<<<SEQ / 16, 512, 0, stream>>>(seq, emb, Wih, bih, bhh, xp);
        lstm_scan<<<1, 512, 0, stream>>>(xp, Whh, fcw, fcb, out);
    } else {
        lstm_scan_small<<<1, 512, 0, stream>>>(seq, emb, Wih, Whh,
                                               bih, bhh, fcw, fcb, out);
    }
}